// Round 13
// baseline (265.605 us; speedup 1.0000x reference)
//
#include <hip/hip_runtime.h>
#include <hip/hip_bf16.h>

// AutoInt fused: embedding gather -> 2x MHSA (32 fields, 4 heads x 32) -> logit.
// R12..R24 history: 2 samples/wave, rcp_fast + paired cvt, fragment-ordered W,
// batch-issued gathers, rolling pre[4] W prefetch, disjoint swizzled y2,
// direct mh loads. 141us/dispatch.
// R25: OPERAND-SWAPPED MFMA KILLS THE LDS TRANSPOSE ROUND-TRIPS. Q/K/exp(P)
//     previously did store->lgkm->read purely to transpose C-layout (lane =
//     column) into A/B-frag layout (lane = row). Swapped mfma(W,y) yields the
//     transposed C directly: lane holds its own row; the missing half-row sits
//     in the h2-partner (lane^32) and is rebuilt with __shfl_xor+cndmask.
//     S^T = mfma(Kfrag,Qfrag) puts P-rows in-lane; exp in-register -> PV
//     A-frag. Only V keeps an LDS tile (PV needs V^T as B-operand; its store
//     was already vectorized). Bit-identical: swapped MFMA is a bitwise
//     transpose (products commute, k-tree fixed); same bf16 packing; same
//     accumulation order. LDS 53,248 -> 36,864B. Barriers stay 4 but the
//     per-phase lgkm serializations are gone.

#define NSAMP 8192
#define S_Y1 72    // layer1 input stride (shorts)
#define S_T 36     // V-tile stride (shorts)

typedef __attribute__((ext_vector_type(8))) short bf8_t;   // 8 bf16 (4 VGPRs)
typedef __attribute__((ext_vector_type(16))) float f16v;   // 32x32 C/D

__device__ __forceinline__ short f2bf(float f) {
  unsigned u = __float_as_uint(f);
  u += 0x7fffu + ((u >> 16) & 1u);   // RNE
  return (short)(u >> 16);
}
// packed RNE f32x2 -> bf16x2; a -> low 16, b -> high 16 (HIP header semantics)
__device__ __forceinline__ unsigned pack2(float a, float b) {
  __hip_bfloat162 h = __float22bfloat162_rn(float2{a, b});
  union { __hip_bfloat162 h2; unsigned u; } cvt;
  cvt.h2 = h;
  return cvt.u;
}
__device__ __forceinline__ float bf2f(short s) {
  return __uint_as_float(((unsigned)(unsigned short)s) << 16);
}
__device__ __forceinline__ float rcp_fast(float x) {
  return __builtin_amdgcn_rcpf(x);   // v_rcp_f32, ~1ulp; sums>0 always
}
__device__ __forceinline__ f16v mfma32(bf8_t a, bf8_t b, f16v c) {
  return __builtin_amdgcn_mfma_f32_32x32x16_bf16(a, b, c, 0, 0, 0);
}

// Rebuild an A/B fragment from a transposed-C quad pair. Own lane holds quads
// a (g=2kc) and b (g=2kc+1); partner (lane^32) holds the complementary dims.
// h2=0 frag = {a01,a23, partner(a01),partner(a23)}; h2=1 = {partner(b01),
// partner(b23), b01, b23}. __shfl_xor(.,32): certain lane^32 semantics.
__device__ __forceinline__ bf8_t xchg(unsigned a01, unsigned a23,
                                      unsigned b01, unsigned b23, int h2) {
  unsigned pa01 = (unsigned)__shfl_xor((int)a01, 32);
  unsigned pa23 = (unsigned)__shfl_xor((int)a23, 32);
  unsigned pb01 = (unsigned)__shfl_xor((int)b01, 32);
  unsigned pb23 = (unsigned)__shfl_xor((int)b23, 32);
  union { bf8_t v; unsigned u[4]; } r;
  r.u[0] = h2 ? pb01 : a01;
  r.u[1] = h2 ? pb23 : a23;
  r.u[2] = h2 ? b01 : pa01;
  r.u[3] = h2 ? b23 : pa23;
  return r.v;
}

// Transposed-C (16 f32, dims (r&3)+8*(r>>2)+4*h2) -> two K=16 A/B fragments.
__device__ __forceinline__ void buildFrag(const f16v& o, int h2, bf8_t (&dst)[2]) {
#pragma unroll
  for (int kc = 0; kc < 2; ++kc) {
    unsigned a01 = pack2(o[8 * kc + 0], o[8 * kc + 1]);
    unsigned a23 = pack2(o[8 * kc + 2], o[8 * kc + 3]);
    unsigned b01 = pack2(o[8 * kc + 4], o[8 * kc + 5]);
    unsigned b23 = pack2(o[8 * kc + 6], o[8 * kc + 7]);
    dst[kc] = xchg(a01, a23, b01, b23, h2);
  }
}

// NORMAL projection (C = y.W^T + b): lane col = out-dim, regs = fields.
// Rolling prefetch: pre[] holds this phase's first 4 W frags; if HAS_NEXT,
// issues the next phase's first 4 into pre.
template<int KS, bool HAS_NEXT>
__device__ __forceinline__ void projPF(const bf8_t (&af)[2][KS],
                                       const short* __restrict__ W,
                                       const float* __restrict__ bias,
                                       int fragBase,
                                       const short* __restrict__ Wnext,
                                       int fbNext, int n0, int col,
                                       bf8_t (&pre)[4], f16v (&o)[2]) {
  constexpr int PF = (KS < 4) ? KS : 4;
  bf8_t nxt[4];
  if constexpr (HAS_NEXT) {
#pragma unroll
    for (int i = 0; i < 4; ++i)
      nxt[i] = *(const bf8_t*)&Wnext[fbNext + i * 512];
  }
  float bb = bias[n0 + col];
#pragma unroll
  for (int i = 0; i < 16; ++i) { o[0][i] = bb; o[1][i] = bb; }
#pragma unroll
  for (int kc = 0; kc < KS; ++kc) {
    bf8_t w;
    if (kc < PF) w = pre[kc];
    else w = *(const bf8_t*)&W[fragBase + kc * 512];
    o[0] = mfma32(af[0][kc], w, o[0]);
    o[1] = mfma32(af[1][kc], w, o[1]);
  }
  if constexpr (HAS_NEXT) {
#pragma unroll
    for (int i = 0; i < 4; ++i) pre[i] = nxt[i];
  }
}

// SWAPPED projection (C^T = W.y^T): lane col = FIELD, regs = out-dims.
// Bias is per-reg: o[4g+r] = bias[n0 + 8g + 4h2 + r] (same logical element,
// same value as the normal orientation -> bit-identical Q/K).
template<int KS, bool HAS_NEXT>
__device__ __forceinline__ void projSwp(const bf8_t (&af)[2][KS],
                                        const short* __restrict__ W,
                                        const float* __restrict__ bias,
                                        int fragBase,
                                        const short* __restrict__ Wnext,
                                        int fbNext, int n0, int h2,
                                        bf8_t (&pre)[4], f16v (&o)[2]) {
  constexpr int PF = (KS < 4) ? KS : 4;
  bf8_t nxt[4];
  if constexpr (HAS_NEXT) {
#pragma unroll
    for (int i = 0; i < 4; ++i)
      nxt[i] = *(const bf8_t*)&Wnext[fbNext + i * 512];
  }
#pragma unroll
  for (int g = 0; g < 4; ++g) {
    float4 b4 = *(const float4*)&bias[n0 + 8 * g + 4 * h2];
    o[0][4 * g + 0] = b4.x; o[0][4 * g + 1] = b4.y;
    o[0][4 * g + 2] = b4.z; o[0][4 * g + 3] = b4.w;
    o[1][4 * g + 0] = b4.x; o[1][4 * g + 1] = b4.y;
    o[1][4 * g + 2] = b4.z; o[1][4 * g + 3] = b4.w;
  }
#pragma unroll
  for (int kc = 0; kc < KS; ++kc) {
    bf8_t w;
    if (kc < PF) w = pre[kc];
    else w = *(const bf8_t*)&W[fragBase + kc * 512];
    o[0] = mfma32(w, af[0][kc], o[0]);   // operands swapped -> C^T
    o[1] = mfma32(w, af[1][kc], o[1]);
  }
  if constexpr (HAS_NEXT) {
#pragma unroll
    for (int i = 0; i < 4; ++i) pre[i] = nxt[i];
  }
}

// One attention layer for this wave's head, BOTH samples. Only V touches an
// LDS tile (wave-private). Q/K/P fragments live entirely in registers.
// L1 (!FUSE): yIn = y1 (overlays heads 0-1 V-tiles -> barrier before V-store).
// L2 (FUSE):  yIn = swizzled y2s (disjoint; V-tiles wave-private -> 0 barriers)
template<int D_IN, bool FUSE>
__device__ void attn_layer(const short* yIn0, const short* yIn1,
                           short* yOut0, short* yOut1,
                           const short* __restrict__ Wq, const short* __restrict__ Wk,
                           const short* __restrict__ Wv, const short* __restrict__ Wr,
                           const float* __restrict__ bq, const float* __restrict__ bk,
                           const float* __restrict__ bvp, const float* __restrict__ br,
                           short* bV0, short* bV1,
                           const short* __restrict__ lwF,
                           const short* __restrict__ WnlQ, int fbNext,
                           int n0, int col, int h2, bf8_t (&pre)[4],
                           float (&pp)[2]) {
  constexpr int KS = D_IN / 16;
  const short* yIn[2] = {yIn0, yIn1};
  short* bV[2] = {bV0, bV1};
  const int head = n0 >> 5;
  const int lane = h2 * 32 + col;
  const int fragBase = head * KS * 512 + lane * 8;

  // A-fragments (y) for both samples
  bf8_t af[2][KS];
#pragma unroll
  for (int sp = 0; sp < 2; ++sp)
#pragma unroll
    for (int kc = 0; kc < KS; ++kc) {
      if constexpr (FUSE) {
        int gsw = (kc * 2 + h2) ^ (col & 15);
        af[sp][kc] = *(const bf8_t*)&yIn[sp][col * 128 + (gsw << 3)];
      } else {
        af[sp][kc] = *(const bf8_t*)&yIn[sp][col * S_Y1 + kc * 16 + h2 * 8];
      }
    }

  f16v acc[2];
  bf8_t afq[2][2], afk[2][2];

  // ---- Q swapped (prefetches Wk) -> in-register A-frags
  projSwp<KS, true>(af, Wq, bq, fragBase, Wk, fragBase, n0, h2, pre, acc);
  buildFrag(acc[0], h2, afq[0]);
  buildFrag(acc[1], h2, afq[1]);

  // ---- K swapped (prefetches Wv) -> in-register B-frags
  projSwp<KS, true>(af, Wk, bk, fragBase, Wv, fragBase, n0, h2, pre, acc);
  buildFrag(acc[0], h2, afk[0]);
  buildFrag(acc[1], h2, afk[1]);

  // ---- V normal (prefetches Wr)
  projPF<KS, true>(af, Wv, bvp, fragBase, Wr, fragBase, n0, col, pre, acc);

  if constexpr (!FUSE)
    __syncthreads();   // all waves' y1 af reads done; V-tiles writable

  // ---- V -> tile transposed (C-native, uint2 writes)
#pragma unroll
  for (int sp = 0; sp < 2; ++sp)
#pragma unroll
    for (int g = 0; g < 4; ++g) {
      uint2 pk;
      pk.x = pack2(acc[sp][g * 4 + 0], acc[sp][g * 4 + 1]);
      pk.y = pack2(acc[sp][g * 4 + 2], acc[sp][g * 4 + 3]);
      *(uint2*)&bV[sp][col * S_T + 8 * g + 4 * h2] = pk;
    }

  // ---- Res normal (layer1: prefetches next layer's Wq; layer2: none)
  f16v res[2];
  projPF<KS, !FUSE>(af, Wr, br, fragBase, WnlQ, fbNext, n0, col, pre, res);

  // ---- S^T = mfma(Kfrag, Qfrag): lane col holds S[q=col][k regs]
  f16v z[2];
#pragma unroll
  for (int sp = 0; sp < 2; ++sp) {
#pragma unroll
    for (int i = 0; i < 16; ++i) z[sp][i] = 0.f;
#pragma unroll
    for (int kc = 0; kc < 2; ++kc)
      z[sp] = mfma32(afk[sp][kc], afq[sp][kc], z[sp]);
  }

  // ---- P = exp(S) in-register -> PV A-frags
  bf8_t pa[2][2];
#pragma unroll
  for (int sp = 0; sp < 2; ++sp) {
    f16v e;
#pragma unroll
    for (int i = 0; i < 16; ++i) e[i] = __expf(z[sp][i]);
    buildFrag(e, h2, pa[sp]);
  }

  // ---- FUSE: hoist logit-weight loads above the PV chain
  short4 l4b[4];
  if constexpr (FUSE) {
#pragma unroll
    for (int g = 0; g < 4; ++g)
      l4b[g] = *(const short4*)&lwF[(head * 4 + g) * 256 + lane * 4];
  }

  // ---- PV + row-sums (all-ones B-frag), then epilogue per sample
  const short onebf = (short)0x3F80;
  bf8_t ones = {onebf, onebf, onebf, onebf, onebf, onebf, onebf, onebf};
  f16v pv[2], sums[2];
#pragma unroll
  for (int sp = 0; sp < 2; ++sp) {
#pragma unroll
    for (int i = 0; i < 16; ++i) { pv[sp][i] = 0.f; sums[sp][i] = 0.f; }
#pragma unroll
    for (int kc = 0; kc < 2; ++kc) {
      bf8_t vb = *(const bf8_t*)&bV[sp][col * S_T + kc * 16 + h2 * 8];
      pv[sp] = mfma32(pa[sp][kc], vb, pv[sp]);
      sums[sp] = mfma32(pa[sp][kc], ones, sums[sp]);
    }
  }

  if constexpr (FUSE) {
#pragma unroll
    for (int g = 0; g < 4; ++g) {
      short4 l4 = l4b[g];
#pragma unroll
      for (int r = 0; r < 4; ++r) {
        int reg = g * 4 + r;
        float lw = bf2f((r == 0) ? l4.x : (r == 1) ? l4.y : (r == 2) ? l4.z : l4.w);
        pp[0] += fmaxf(fmaf(pv[0][reg], rcp_fast(sums[0][reg]), res[0][reg]), 0.f) * lw;
        pp[1] += fmaxf(fmaf(pv[1][reg], rcp_fast(sums[1][reg]), res[1][reg]), 0.f) * lw;
      }
    }
  } else {
    // Swizzled y2 write; y2s disjoint from tiles -> NO barrier needed.
    short* yOut[2] = {yOut0, yOut1};
    const int cg = head * 4 + (col >> 3);   // column granule
    const int cw = col & 7;                  // within-granule
#pragma unroll
    for (int sp = 0; sp < 2; ++sp)
#pragma unroll
      for (int g = 0; g < 4; ++g) {
        float v[4];
#pragma unroll
        for (int r = 0; r < 4; ++r)
          v[r] = fmaxf(fmaf(pv[sp][4 * g + r], rcp_fast(sums[sp][4 * g + r]),
                            res[sp][4 * g + r]), 0.f);
        unsigned p01 = pack2(v[0], v[1]);
        unsigned p23 = pack2(v[2], v[3]);
        int rb = 8 * g + 4 * h2;
        short s4[4] = {(short)(p01 & 0xffffu), (short)(p01 >> 16),
                       (short)(p23 & 0xffffu), (short)(p23 >> 16)};
#pragma unroll
        for (int r = 0; r < 4; ++r) {
          int row = rb + r;
          yOut[sp][row * 128 + ((cg ^ (row & 15)) << 3) + cw] = s4[r];
        }
      }
  }
}

__global__ __launch_bounds__(256, 3) void autoint_main(
    const int* __restrict__ onehot_i, const float* __restrict__ onehot_x,
    const int* __restrict__ mh_i, const float* __restrict__ mh_x,
    const float* __restrict__ ctns, const float* __restrict__ xx,
    const float* __restrict__ xy,
    const float* __restrict__ bq1, const float* __restrict__ bk1,
    const float* __restrict__ bv1, const float* __restrict__ br1,
    const float* __restrict__ bq2, const float* __restrict__ bk2,
    const float* __restrict__ bv2, const float* __restrict__ br2,
    const float* __restrict__ logitb, const short* __restrict__ wbf,
    float* __restrict__ out) {
  // scr: per-sample 4 wave-private V-tiles (1152 shorts each). y1 (2304
  // shorts/sample, stride 72) overlays heads 0-1 V-tiles, fenced by the
  // in-layer barrier. y2s: disjoint XOR-swizzled y2 [32][128] per sample.
  // Total LDS = 18,432 + 16,384 = 34,816 B -> 36,864 granule-rounded.
  __shared__ __align__(16) short scr[2][4608];
  __shared__ __align__(16) short y2s[2][4096];

  const int t = threadIdx.x;
  const int head = t >> 6;
  const int lane = t & 63;
  const int col = lane & 31;
  const int h2 = lane >> 5;
  const int n0 = head * 32;
  const int s0 = blockIdx.x * 2;

  short* bV0 = &scr[0][head * 1152];
  short* bV1 = &scr[1][head * 1152];

  // ---- rolling W prefetch: Wq1 frags 0..3 issued NOW, hidden under embedding
  const int fb1 = head * 4 * 512 + lane * 8;
  const int fb2 = head * 8 * 512 + lane * 8;
  bf8_t pre[4];
#pragma unroll
  for (int i = 0; i < 4; ++i) pre[i] = *(const bf8_t*)&wbf[fb1 + i * 512];

  const int e4 = t & 15, f0 = t >> 4;

  // ---- E0: onehot scalars + ctns/xy
  int oh_r[2][2]; float oh_w[2][2];        // [chunk][se]
#pragma unroll
  for (int se = 0; se < 2; ++se) {
    oh_r[0][se] = onehot_i[(s0 + se) * 20 + f0];
    oh_w[0][se] = onehot_x[(s0 + se) * 20 + f0];
  }
  if (t < 64) {
#pragma unroll
    for (int se = 0; se < 2; ++se) {
      oh_r[1][se] = onehot_i[(s0 + se) * 20 + 16 + f0];
      oh_w[1][se] = onehot_x[(s0 + se) * 20 + 16 + f0];
    }
  }
  if (t < 160) {                           // ctns: rows 22..31
    int ci = t >> 4;
    float4 xv = *(const float4*)&xy[ci * 64 + e4 * 4];
    float cv0 = ctns[(s0 + 0) * 10 + ci];
    float cv1 = ctns[(s0 + 1) * 10 + ci];
    uint2 w0; w0.x = pack2(cv0 * xv.x, cv0 * xv.y); w0.y = pack2(cv0 * xv.z, cv0 * xv.w);
    *(uint2*)&scr[0][(22 + ci) * S_Y1 + e4 * 4] = w0;
    uint2 w1; w1.x = pack2(cv1 * xv.x, cv1 * xv.y); w1.y = pack2(cv1 * xv.z, cv1 * xv.w);
    *(uint2*)&scr[1][(22 + ci) * S_Y1 + e4 * 4] = w1;
  }

  // ---- E2a: onehot gathers issue (fly alongside mh idx reads + gathers)
  float4 g0[2], g1[2];
#pragma unroll
  for (int se = 0; se < 2; ++se)
    g0[se] = *(const float4*)&xx[oh_r[0][se] * 64 + e4 * 4];
  if (t < 64) {
#pragma unroll
    for (int se = 0; se < 2; ++se)
      g1[se] = *(const float4*)&xx[oh_r[1][se] * 64 + e4 * 4];
  }

  // ---- E1: multihot, DIRECT global idx/weight loads (wave-merged, L2-hot),
  //      7-deep batch-issued gathers (k padded to 56), 8-lane shfl reduce.
  {
    const int slot = t >> 3, ks = t & 7;
    const int j = slot >> 4, e4m = slot & 15;
#pragma unroll
    for (int se = 0; se < 2; ++se) {
      const int sg = s0 + se;
      const int* ip = &mh_i[(j * NSAMP + sg) * 50];
      const float* xp = &mh_x[(j * NSAMP + sg) * 50];
      int rw[7]; float wt[7];
#pragma unroll
      for (int i = 0; i < 7; ++i) {
        int k = ks + 8 * i;
        int ok = (k < 50);
        rw[i] = ok ? ip[k] : 0;
        wt[i] = ok ? xp[k] : 0.f;
      }
      float4 xv[7];
#pragma unroll
      for (int i = 0; i < 7; ++i)
        xv[i] = *(const float4*)&xx[rw[i] * 64 + e4m * 4];
      float a0 = 0.f, a1 = 0.f, a2 = 0.f, a3 = 0.f;
#pragma unroll
      for (int i = 0; i < 7; ++i) {
        a0 += xv[i].x * wt[i]; a1 += xv[i].y * wt[i];
        a2 += xv[i].z * wt[i]; a3 += xv[i].w * wt[i];
      }
#pragma unroll
      for (int d = 1; d < 8; d <<= 1) {
        a0 += __shfl_xor(a0, d); a1 += __shfl_xor(a1, d);
        a2 += __shfl_xor(a2, d); a3 += __shfl_xor(a3, d);
      }
      if (ks == 0) {
        uint2 w; w.x = pack2(a0, a1); w.y = pack2(a2, a3);
        *(uint2*)&scr[se][(20 + j) * S_Y1 + e4m * 4] = w;
      }
    }
  }

  // ---- E2b: onehot scale + store (gathers long since landed)
#pragma unroll
  for (int se = 0; se < 2; ++se) {
    float xw = oh_w[0][se];
    uint2 w; w.x = pack2(g0[se].x * xw, g0[se].y * xw);
    w.y = pack2(g0[se].z * xw, g0[se].w * xw);
    *(uint2*)&scr[se][f0 * S_Y1 + e4 * 4] = w;
  }
  if (t < 64) {
#pragma unroll
    for (int se = 0; se < 2; ++se) {
      float xw = oh_w[1][se];
      uint2 w; w.x = pack2(g1[se].x * xw, g1[se].y * xw);
      w.y = pack2(g1[se].z * xw, g1[se].w * xw);
      *(uint2*)&scr[se][(16 + f0) * S_Y1 + e4 * 4] = w;
    }
  }
  __syncthreads();   // y1 complete

  float pp[2] = {0.f, 0.f};
  attn_layer<64, false>(&scr[0][0], &scr[1][0], &y2s[0][0], &y2s[1][0],
      wbf + 0, wbf + 8192, wbf + 16384, wbf + 24576,
      bq1, bk1, bv1, br1, bV0, bV1, nullptr,
      wbf + 32768, fb2, n0, col, h2, pre, pp);
  __syncthreads();   // y2s fully written before layer2 af reads
  attn_layer<128, true>(&y2s[0][0], &y2s[1][0], nullptr, nullptr,
      wbf + 32768, wbf + 49152, wbf + 65536, wbf + 81920,
      bq2, bk2, bv2, br2, bV0, bV1, wbf + 98304,
      wbf, 0, n0, col, h2, pre, pp);

  // ---- logit partials: wave-reduce each sample; partials go into each
  //      wave's OWN dead V-tile (last tile read was this wave's PV).
  float* red0 = (float*)bV0;
  float* red1 = (float*)bV1;
#pragma unroll
  for (int off = 32; off > 0; off >>= 1) {
    pp[0] += __shfl_xor(pp[0], off);
    pp[1] += __shfl_xor(pp[1], off);
  }
  if (lane == 0) { red0[0] = pp[0]; red1[0] = pp[1]; }
  __syncthreads();
  if (t < 2) {
    const short* base = t == 0 ? &scr[0][0] : &scr[1][0];
    float zz = logitb[0];
#pragma unroll
    for (int h = 0; h < 4; ++h)
      zz += *(const float*)&base[h * 1152];
    out[s0 + t] = 1.f / (1.f + __expf(-zz));
  }
}

// fp32 -> bf16 weight conversion into ws, FRAGMENT-ORDERED:
// [0)Wq1F [8192)Wk1F [16384)Wv1F [24576)Wr1F   each ((h*4+kc)*64+lane)*8+e
// [32768)Wq2F [49152)Wk2F [65536)Wv2F [81920)Wr2F  ((h*8+kc)*64+lane)*8+e
// [98304)lwF ((h*4+g)*64+lane)*4+r = lw[(8g+4h2+r)*128 + h*32+col]
__global__ void convert_w(const float* __restrict__ qw1, const float* __restrict__ kw1,
                          const float* __restrict__ vw1, const float* __restrict__ rw1,
                          const float* __restrict__ qw2, const float* __restrict__ kw2,
                          const float* __restrict__ vw2, const float* __restrict__ rw2,
                          const float* __restrict__ lw, short* __restrict__ outw) {
  int i = blockIdx.x * 256 + threadIdx.x;
  if (i >= 102400) return;
  float v;
  if (i < 32768) {
    int tsel = i >> 13, d = i & 8191;
    int e = d & 7, lane = (d >> 3) & 63, kc = (d >> 9) & 3, h = (d >> 11) & 3;
    int col = lane & 31, h2 = lane >> 5;
    int j = (h * 32 + col) * 64 + kc * 16 + h2 * 8 + e;
    const float* src = tsel == 0 ? qw1 : tsel == 1 ? kw1 : tsel == 2 ? vw1 : rw1;
    v = src[j];
  } else if (i < 98304) {
    int k = i - 32768;
    int tsel = k >> 14, d = k & 16383;
    int e = d & 7, lane = (d >> 3) & 63, kc = (d >> 9) & 7, h = (d >> 12) & 3;
    int col = lane & 31, h2 = lane >> 5;
    int j = (h * 32 + col) * 128 + kc * 16 + h2 * 8 + e;
    const float* src = tsel == 0 ? qw2 : tsel == 1 ? kw2 : tsel == 2 ? vw2 : rw2;
    v = src[j];
  } else {
    int d = i - 98304;
    int r = d & 3, lane = (d >> 2) & 63, g = (d >> 8) & 3, h = (d >> 10) & 3;
    int col = lane & 31, h2 = lane >> 5;
    v = lw[(8 * g + 4 * h2 + r) * 128 + h * 32 + col];
  }
  outw[i] = f2bf(v);
}

extern "C" void kernel_launch(void* const* d_in, const int* in_sizes, int n_in,
                              void* d_out, int out_size, void* d_ws, size_t ws_size,
                              hipStream_t stream) {
  short* wbf = (short*)d_ws;  // 204800 bytes used
  convert_w<<<400, 256, 0, stream>>>(
      (const float*)d_in[7], (const float*)d_in[9], (const float*)d_in[11],
      (const float*)d_in[13], (const float*)d_in[15], (const float*)d_in[17],
      (const float*)d_in[19], (const float*)d_in[21], (const float*)d_in[23], wbf);
  autoint_main<<<NSAMP / 2, 256, 0, stream>>>(
      (const int*)d_in[0], (const float*)d_in[1], (const int*)d_in[2],
      (const float*)d_in[3], (const float*)d_in[4], (const float*)d_in[5],
      (const float*)d_in[6],
      (const float*)d_in[8], (const float*)d_in[10], (const float*)d_in[12],
      (const float*)d_in[14], (const float*)d_in[16], (const float*)d_in[18],
      (const float*)d_in[20], (const float*)d_in[22], (const float*)d_in[24],
      wbf, (float*)d_out);
}

// Round 14
// 241.698 us; speedup vs baseline: 1.0989x; 1.0989x over previous
//
#include <hip/hip_runtime.h>
#include <hip/hip_bf16.h>

// AutoInt fused: embedding gather -> 2x MHSA (32 fields, 4 heads x 32) -> logit.
// R12..R24: 2 samples/wave, rcp_fast + paired cvt, fragment-ordered W, batch
// gathers, rolling pre[4] W prefetch, disjoint swizzled y2, direct mh loads
// = 141us. R25 (full in-register Q/K/P) spilled (176 regs > 170 cap) BUT
// passed bit-exact -> xchg/buildFrag wiring proven.
// R26: REGISTER-SAFE SUBSET of R25. Q/K keep their LDS tiles (cheap, caps
//     pressure); only exp(P)'s round-trip is eliminated: QK^T is operand-
//     swapped (z = mfma(kb,qa) -> P-rows in-lane), exp in-register, pa via
//     buildFrag. Phases reordered Q,K,S,exp,V,R so fragment sets never
//     overlap (peak ~144 regs = R12's budget). V stores into bK (dead after
//     QK^T). Prefetch chain: Q->Wk, K->Wv, V->Wr, R->WnlQ. Bit-identical.

#define NSAMP 8192
#define S_Y1 72    // layer1 input stride (shorts)
#define S_T 36     // 32x32 tile stride (shorts)

typedef __attribute__((ext_vector_type(8))) short bf8_t;   // 8 bf16 (4 VGPRs)
typedef __attribute__((ext_vector_type(16))) float f16v;   // 32x32 C/D

__device__ __forceinline__ short f2bf(float f) {
  unsigned u = __float_as_uint(f);
  u += 0x7fffu + ((u >> 16) & 1u);   // RNE
  return (short)(u >> 16);
}
// packed RNE f32x2 -> bf16x2; a -> low 16, b -> high 16 (HIP header semantics)
__device__ __forceinline__ unsigned pack2(float a, float b) {
  __hip_bfloat162 h = __float22bfloat162_rn(float2{a, b});
  union { __hip_bfloat162 h2; unsigned u; } cvt;
  cvt.h2 = h;
  return cvt.u;
}
__device__ __forceinline__ float bf2f(short s) {
  return __uint_as_float(((unsigned)(unsigned short)s) << 16);
}
__device__ __forceinline__ float rcp_fast(float x) {
  return __builtin_amdgcn_rcpf(x);   // v_rcp_f32, ~1ulp; sums>0 always
}
__device__ __forceinline__ f16v mfma32(bf8_t a, bf8_t b, f16v c) {
  return __builtin_amdgcn_mfma_f32_32x32x16_bf16(a, b, c, 0, 0, 0);
}

// Rebuild an A-fragment from a transposed-C quad pair (proven bit-exact in
// R25's full run). Own lane holds quads a(g=2kc), b(g=2kc+1); partner
// (lane^32) holds the complementary dims.
__device__ __forceinline__ bf8_t xchg(unsigned a01, unsigned a23,
                                      unsigned b01, unsigned b23, int h2) {
  unsigned pa01 = (unsigned)__shfl_xor((int)a01, 32);
  unsigned pa23 = (unsigned)__shfl_xor((int)a23, 32);
  unsigned pb01 = (unsigned)__shfl_xor((int)b01, 32);
  unsigned pb23 = (unsigned)__shfl_xor((int)b23, 32);
  union { bf8_t v; unsigned u[4]; } r;
  r.u[0] = h2 ? pb01 : a01;
  r.u[1] = h2 ? pb23 : a23;
  r.u[2] = h2 ? b01 : pa01;
  r.u[3] = h2 ? b23 : pa23;
  return r.v;
}

// Transposed-C (16 f32, k-dims (r&3)+8*(r>>2)+4*h2) -> two K=16 A-fragments.
__device__ __forceinline__ void buildFrag(const f16v& o, int h2, bf8_t (&dst)[2]) {
#pragma unroll
  for (int kc = 0; kc < 2; ++kc) {
    unsigned a01 = pack2(o[8 * kc + 0], o[8 * kc + 1]);
    unsigned a23 = pack2(o[8 * kc + 2], o[8 * kc + 3]);
    unsigned b01 = pack2(o[8 * kc + 4], o[8 * kc + 5]);
    unsigned b23 = pack2(o[8 * kc + 6], o[8 * kc + 7]);
    dst[kc] = xchg(a01, a23, b01, b23, h2);
  }
}

// Projection with rolling W prefetch. pre[] holds this phase's first 4
// fragments (issued during the PREVIOUS phase); fragments 4..KS load here.
// If HAS_NEXT, issues the next phase's first 4 fragments into pre.
template<int KS, bool HAS_NEXT>
__device__ __forceinline__ void projPF(const bf8_t (&af)[2][KS],
                                       const short* __restrict__ W,
                                       const float* __restrict__ bias,
                                       int fragBase,
                                       const short* __restrict__ Wnext,
                                       int fbNext, int n0, int col,
                                       bf8_t (&pre)[4], f16v (&o)[2]) {
  constexpr int PF = (KS < 4) ? KS : 4;
  bf8_t nxt[4];
  if constexpr (HAS_NEXT) {
#pragma unroll
    for (int i = 0; i < 4; ++i)
      nxt[i] = *(const bf8_t*)&Wnext[fbNext + i * 512];
  }
  float bb = bias[n0 + col];
#pragma unroll
  for (int i = 0; i < 16; ++i) { o[0][i] = bb; o[1][i] = bb; }
#pragma unroll
  for (int kc = 0; kc < KS; ++kc) {
    bf8_t w;
    if (kc < PF) w = pre[kc];
    else w = *(const bf8_t*)&W[fragBase + kc * 512];
    o[0] = mfma32(af[0][kc], w, o[0]);
    o[1] = mfma32(af[1][kc], w, o[1]);
  }
  if constexpr (HAS_NEXT) {
#pragma unroll
    for (int i = 0; i < 4; ++i) pre[i] = nxt[i];
  }
}

// Store one C-fragment quad (regs 4g..4g+3 -> rows 8g+4h2..+3, same col).
__device__ __forceinline__ void storeQuad(short* tile, int stride, int g, int h2,
                                          int col, float a0, float a1, float a2,
                                          float a3) {
  unsigned p01 = pack2(a0, a1);
  unsigned p23 = pack2(a2, a3);
  int rb = 8 * g + 4 * h2;
  tile[(rb + 0) * stride + col] = (short)(p01 & 0xffffu);
  tile[(rb + 1) * stride + col] = (short)(p01 >> 16);
  tile[(rb + 2) * stride + col] = (short)(p23 & 0xffffu);
  tile[(rb + 3) * stride + col] = (short)(p23 >> 16);
}

// One attention layer for this wave's head, BOTH samples. pre[] carries the
// rolling W prefetch. Tiles bQ/bK are WAVE-PRIVATE (per sample,head).
// Phase order: Q->bQ, K->bK, QK^T swapped -> exp in-reg -> pa, V->bK (dead),
// R->res, PV. No exp LDS round-trip.
template<int D_IN, bool FUSE>
__device__ void attn_layer(const short* yIn0, const short* yIn1,
                           short* yOut0, short* yOut1,
                           const short* __restrict__ Wq, const short* __restrict__ Wk,
                           const short* __restrict__ Wv, const short* __restrict__ Wr,
                           const float* __restrict__ bq, const float* __restrict__ bk,
                           const float* __restrict__ bvp, const float* __restrict__ br,
                           short* bQ0, short* bK0, short* bQ1, short* bK1,
                           const short* __restrict__ lwF,
                           const short* __restrict__ WnlQ, int fbNext,
                           int n0, int col, int h2, bf8_t (&pre)[4],
                           float (&pp)[2]) {
  constexpr int KS = D_IN / 16;
  const short* yIn[2] = {yIn0, yIn1};
  short* bQ[2] = {bQ0, bQ1};
  short* bK[2] = {bK0, bK1};
  const int head = n0 >> 5;
  const int lane = h2 * 32 + col;
  const int fragBase = head * KS * 512 + lane * 8;

  // A-fragments for both samples
  bf8_t af[2][KS];
#pragma unroll
  for (int sp = 0; sp < 2; ++sp)
#pragma unroll
    for (int kc = 0; kc < KS; ++kc) {
      if constexpr (FUSE) {
        // swizzled y2: row = col, granule = kc*2+h2
        int gsw = (kc * 2 + h2) ^ (col & 15);
        af[sp][kc] = *(const bf8_t*)&yIn[sp][col * 128 + (gsw << 3)];
      } else {
        af[sp][kc] = *(const bf8_t*)&yIn[sp][col * S_Y1 + kc * 16 + h2 * 8];
      }
    }
  if constexpr (!FUSE)
    __syncthreads();   // y1 overlay dead before tile writes

  f16v acc[2];

  // ---- Q (prefetches Wk) -> bQ row-major
  projPF<KS, true>(af, Wq, bq, fragBase, Wk, fragBase, n0, col, pre, acc);
#pragma unroll
  for (int sp = 0; sp < 2; ++sp)
#pragma unroll
    for (int g = 0; g < 4; ++g)
      storeQuad(bQ[sp], S_T, g, h2, col, acc[sp][4 * g + 0], acc[sp][4 * g + 1],
                acc[sp][4 * g + 2], acc[sp][4 * g + 3]);

  // ---- K (prefetches Wv) -> bK row-major
  projPF<KS, true>(af, Wk, bk, fragBase, Wv, fragBase, n0, col, pre, acc);
#pragma unroll
  for (int sp = 0; sp < 2; ++sp)
#pragma unroll
    for (int g = 0; g < 4; ++g)
      storeQuad(bK[sp], S_T, g, h2, col, acc[sp][4 * g + 0], acc[sp][4 * g + 1],
                acc[sp][4 * g + 2], acc[sp][4 * g + 3]);

  // ---- S^T = mfma(kb, qa): P-rows land in-lane; exp in-register -> pa.
  // (Swapped MFMA is a bitwise transpose; buildFrag wiring proven in R25.)
  bf8_t pa[2][2];
#pragma unroll
  for (int sp = 0; sp < 2; ++sp) {
    f16v z;
#pragma unroll
    for (int i = 0; i < 16; ++i) z[i] = 0.f;
#pragma unroll
    for (int kc = 0; kc < 2; ++kc) {
      bf8_t qa = *(const bf8_t*)&bQ[sp][col * S_T + kc * 16 + h2 * 8];
      bf8_t kb = *(const bf8_t*)&bK[sp][col * S_T + kc * 16 + h2 * 8];
      z = mfma32(kb, qa, z);   // swapped -> S^T
    }
    f16v e;
#pragma unroll
    for (int i = 0; i < 16; ++i) e[i] = __expf(z[i]);
    buildFrag(e, h2, pa[sp]);
  }

  // ---- V (prefetches Wr) -> bK transposed (bK dead after QK^T)
  projPF<KS, true>(af, Wv, bvp, fragBase, Wr, fragBase, n0, col, pre, acc);
#pragma unroll
  for (int sp = 0; sp < 2; ++sp)
#pragma unroll
    for (int g = 0; g < 4; ++g) {
      uint2 pk;
      pk.x = pack2(acc[sp][g * 4 + 0], acc[sp][g * 4 + 1]);
      pk.y = pack2(acc[sp][g * 4 + 2], acc[sp][g * 4 + 3]);
      *(uint2*)&bK[sp][col * S_T + 8 * g + 4 * h2] = pk;
    }

  // ---- Res (layer1: prefetches next layer's Wq; layer2: none)
  f16v res[2];
  projPF<KS, !FUSE>(af, Wr, br, fragBase, WnlQ, fbNext, n0, col, pre, res);

  // ---- FUSE: hoist logit-weight loads above the PV chain
  short4 l4b[4];
  if constexpr (FUSE) {
#pragma unroll
    for (int g = 0; g < 4; ++g)
      l4b[g] = *(const short4*)&lwF[(head * 4 + g) * 256 + lane * 4];
  }

  // ---- PV + row-sums (all-ones B-frag), then epilogue per sample
  const short onebf = (short)0x3F80;
  bf8_t ones = {onebf, onebf, onebf, onebf, onebf, onebf, onebf, onebf};
  f16v pv[2], sums[2];
#pragma unroll
  for (int sp = 0; sp < 2; ++sp) {
#pragma unroll
    for (int i = 0; i < 16; ++i) { pv[sp][i] = 0.f; sums[sp][i] = 0.f; }
#pragma unroll
    for (int kc = 0; kc < 2; ++kc) {
      bf8_t vb = *(const bf8_t*)&bK[sp][col * S_T + kc * 16 + h2 * 8];
      pv[sp] = mfma32(pa[sp][kc], vb, pv[sp]);
      sums[sp] = mfma32(pa[sp][kc], ones, sums[sp]);
    }
  }

  if constexpr (FUSE) {
#pragma unroll
    for (int g = 0; g < 4; ++g) {
      short4 l4 = l4b[g];
#pragma unroll
      for (int r = 0; r < 4; ++r) {
        int reg = g * 4 + r;
        float lw = bf2f((r == 0) ? l4.x : (r == 1) ? l4.y : (r == 2) ? l4.z : l4.w);
        pp[0] += fmaxf(fmaf(pv[0][reg], rcp_fast(sums[0][reg]), res[0][reg]), 0.f) * lw;
        pp[1] += fmaxf(fmaf(pv[1][reg], rcp_fast(sums[1][reg]), res[1][reg]), 0.f) * lw;
      }
    }
  } else {
    // Swizzled y2 write; y2s disjoint from tiles -> NO barrier needed.
    short* yOut[2] = {yOut0, yOut1};
    const int cg = head * 4 + (col >> 3);   // column granule
    const int cw = col & 7;                  // within-granule
#pragma unroll
    for (int sp = 0; sp < 2; ++sp)
#pragma unroll
      for (int g = 0; g < 4; ++g) {
        float v[4];
#pragma unroll
        for (int r = 0; r < 4; ++r)
          v[r] = fmaxf(fmaf(pv[sp][4 * g + r], rcp_fast(sums[sp][4 * g + r]),
                            res[sp][4 * g + r]), 0.f);
        unsigned p01 = pack2(v[0], v[1]);
        unsigned p23 = pack2(v[2], v[3]);
        int rb = 8 * g + 4 * h2;
        short s4[4] = {(short)(p01 & 0xffffu), (short)(p01 >> 16),
                       (short)(p23 & 0xffffu), (short)(p23 >> 16)};
#pragma unroll
        for (int r = 0; r < 4; ++r) {
          int row = rb + r;
          yOut[sp][row * 128 + ((cg ^ (row & 15)) << 3) + cw] = s4[r];
        }
      }
  }
}

__global__ __launch_bounds__(256, 3) void autoint_main(
    const int* __restrict__ onehot_i, const float* __restrict__ onehot_x,
    const int* __restrict__ mh_i, const float* __restrict__ mh_x,
    const float* __restrict__ ctns, const float* __restrict__ xx,
    const float* __restrict__ xy,
    const float* __restrict__ bq1, const float* __restrict__ bk1,
    const float* __restrict__ bv1, const float* __restrict__ br1,
    const float* __restrict__ bq2, const float* __restrict__ bk2,
    const float* __restrict__ bv2, const float* __restrict__ br2,
    const float* __restrict__ logitb, const short* __restrict__ wbf,
    float* __restrict__ out) {
  // scr: per-sample 8 wave-private head-tiles (y1 overlays heads 0-1 tiles).
  // y2s: disjoint XOR-swizzled y2 [32][128] per sample.
  // Total LDS = 36,864 + 16,384 = 53,248 B = 26 x 2KB -> 3 blocks/CU.
  __shared__ __align__(16) short scr[2][9216];
  __shared__ __align__(16) short y2s[2][4096];

  const int t = threadIdx.x;
  const int head = t >> 6;
  const int lane = t & 63;
  const int col = lane & 31;
  const int h2 = lane >> 5;
  const int n0 = head * 32;
  const int s0 = blockIdx.x * 2;

  short* bQ0 = &scr[0][(head * 2 + 0) * 1152];
  short* bK0 = &scr[0][(head * 2 + 1) * 1152];
  short* bQ1 = &scr[1][(head * 2 + 0) * 1152];
  short* bK1 = &scr[1][(head * 2 + 1) * 1152];

  // ---- rolling W prefetch: Wq1 frags 0..3 issued NOW, hidden under embedding
  const int fb1 = head * 4 * 512 + lane * 8;
  const int fb2 = head * 8 * 512 + lane * 8;
  bf8_t pre[4];
#pragma unroll
  for (int i = 0; i < 4; ++i) pre[i] = *(const bf8_t*)&wbf[fb1 + i * 512];

  const int e4 = t & 15, f0 = t >> 4;

  // ---- E0: onehot scalars + ctns/xy
  int oh_r[2][2]; float oh_w[2][2];        // [chunk][se]
#pragma unroll
  for (int se = 0; se < 2; ++se) {
    oh_r[0][se] = onehot_i[(s0 + se) * 20 + f0];
    oh_w[0][se] = onehot_x[(s0 + se) * 20 + f0];
  }
  if (t < 64) {
#pragma unroll
    for (int se = 0; se < 2; ++se) {
      oh_r[1][se] = onehot_i[(s0 + se) * 20 + 16 + f0];
      oh_w[1][se] = onehot_x[(s0 + se) * 20 + 16 + f0];
    }
  }
  if (t < 160) {                           // ctns: rows 22..31
    int ci = t >> 4;
    float4 xv = *(const float4*)&xy[ci * 64 + e4 * 4];
    float cv0 = ctns[(s0 + 0) * 10 + ci];
    float cv1 = ctns[(s0 + 1) * 10 + ci];
    uint2 w0; w0.x = pack2(cv0 * xv.x, cv0 * xv.y); w0.y = pack2(cv0 * xv.z, cv0 * xv.w);
    *(uint2*)&scr[0][(22 + ci) * S_Y1 + e4 * 4] = w0;
    uint2 w1; w1.x = pack2(cv1 * xv.x, cv1 * xv.y); w1.y = pack2(cv1 * xv.z, cv1 * xv.w);
    *(uint2*)&scr[1][(22 + ci) * S_Y1 + e4 * 4] = w1;
  }

  // ---- E2a: onehot gathers issue (fly alongside mh idx reads + gathers)
  float4 g0[2], g1[2];
#pragma unroll
  for (int se = 0; se < 2; ++se)
    g0[se] = *(const float4*)&xx[oh_r[0][se] * 64 + e4 * 4];
  if (t < 64) {
#pragma unroll
    for (int se = 0; se < 2; ++se)
      g1[se] = *(const float4*)&xx[oh_r[1][se] * 64 + e4 * 4];
  }

  // ---- E1: multihot, DIRECT global idx/weight loads (wave-merged, L2-hot),
  //      7-deep batch-issued gathers (k padded to 56), 8-lane shfl reduce.
  {
    const int slot = t >> 3, ks = t & 7;
    const int j = slot >> 4, e4m = slot & 15;
#pragma unroll
    for (int se = 0; se < 2; ++se) {
      const int sg = s0 + se;
      const int* ip = &mh_i[(j * NSAMP + sg) * 50];
      const float* xp = &mh_x[(j * NSAMP + sg) * 50];
      int rw[7]; float wt[7];
#pragma unroll
      for (int i = 0; i < 7; ++i) {
        int k = ks + 8 * i;
        int ok = (k < 50);
        rw[i] = ok ? ip[k] : 0;
        wt[i] = ok ? xp[k] : 0.f;
      }
      float4 xv[7];
#pragma unroll
      for (int i = 0; i < 7; ++i)
        xv[i] = *(const float4*)&xx[rw[i] * 64 + e4m * 4];
      float a0 = 0.f, a1 = 0.f, a2 = 0.f, a3 = 0.f;
#pragma unroll
      for (int i = 0; i < 7; ++i) {
        a0 += xv[i].x * wt[i]; a1 += xv[i].y * wt[i];
        a2 += xv[i].z * wt[i]; a3 += xv[i].w * wt[i];
      }
#pragma unroll
      for (int d = 1; d < 8; d <<= 1) {
        a0 += __shfl_xor(a0, d); a1 += __shfl_xor(a1, d);
        a2 += __shfl_xor(a2, d); a3 += __shfl_xor(a3, d);
      }
      if (ks == 0) {
        uint2 w; w.x = pack2(a0, a1); w.y = pack2(a2, a3);
        *(uint2*)&scr[se][(20 + j) * S_Y1 + e4m * 4] = w;
      }
    }
  }

  // ---- E2b: onehot scale + store (gathers long since landed)
#pragma unroll
  for (int se = 0; se < 2; ++se) {
    float xw = oh_w[0][se];
    uint2 w; w.x = pack2(g0[se].x * xw, g0[se].y * xw);
    w.y = pack2(g0[se].z * xw, g0[se].w * xw);
    *(uint2*)&scr[se][f0 * S_Y1 + e4 * 4] = w;
  }
  if (t < 64) {
#pragma unroll
    for (int se = 0; se < 2; ++se) {
      float xw = oh_w[1][se];
      uint2 w; w.x = pack2(g1[se].x * xw, g1[se].y * xw);
      w.y = pack2(g1[se].z * xw, g1[se].w * xw);
      *(uint2*)&scr[se][(16 + f0) * S_Y1 + e4 * 4] = w;
    }
  }
  __syncthreads();   // y1 complete

  float pp[2] = {0.f, 0.f};
  attn_layer<64, false>(&scr[0][0], &scr[1][0], &y2s[0][0], &y2s[1][0],
      wbf + 0, wbf + 8192, wbf + 16384, wbf + 24576,
      bq1, bk1, bv1, br1, bQ0, bK0, bQ1, bK1, nullptr,
      wbf + 32768, fb2, n0, col, h2, pre, pp);
  __syncthreads();   // y2s fully written before layer2 af reads
  attn_layer<128, true>(&y2s[0][0], &y2s[1][0], nullptr, nullptr,
      wbf + 32768, wbf + 49152, wbf + 65536, wbf + 81920,
      bq2, bk2, bv2, br2, bQ0, bK0, bQ1, bK1, wbf + 98304,
      wbf, 0, n0, col, h2, pre, pp);

  // ---- logit partials: wave-reduce each sample; partials go into each
  //      wave's OWN dead bQ tile (last tile read was this wave's PV).
  float* red0 = (float*)bQ0;
  float* red1 = (float*)bQ1;
#pragma unroll
  for (int off = 32; off > 0; off >>= 1) {
    pp[0] += __shfl_xor(pp[0], off);
    pp[1] += __shfl_xor(pp[1], off);
  }
  if (lane == 0) { red0[0] = pp[0]; red1[0] = pp[1]; }
  __syncthreads();
  if (t < 2) {
    const short* base = t == 0 ? &scr[0][0] : &scr[1][0];
    float zz = logitb[0];
#pragma unroll
    for (int h = 0; h < 4; ++h)
      zz += *(const float*)&base[(h * 2) * 1152];
    out[s0 + t] = 1.f / (1.f + __expf(-zz));
  }
}

// fp32 -> bf16 weight conversion into ws, FRAGMENT-ORDERED:
// [0)Wq1F [8192)Wk1F [16384)Wv1F [24576)Wr1F   each ((h*4+kc)*64+lane)*8+e
// [32768)Wq2F [49152)Wk2F [65536)Wv2F [81920)Wr2F  ((h*8+kc)*64+lane)*8+e
// [98304)lwF ((h*4+g)*64+lane)*4+r = lw[(8g+4h2+r)*128 + h*32+col]
__global__ void convert_w(const float* __restrict__ qw1, const float* __restrict__ kw1,
                          const float* __restrict__ vw1, const float* __restrict__ rw1,
                          const float* __restrict__ qw2, const float* __restrict__ kw2,
                          const float* __restrict__ vw2, const float* __restrict__ rw2,
                          const float* __restrict__ lw, short* __restrict__ outw) {
  int i = blockIdx.x * 256 + threadIdx.x;
  if (i >= 102400) return;
  float v;
  if (i < 32768) {
    int tsel = i >> 13, d = i & 8191;
    int e = d & 7, lane = (d >> 3) & 63, kc = (d >> 9) & 3, h = (d >> 11) & 3;
    int col = lane & 31, h2 = lane >> 5;
    int j = (h * 32 + col) * 64 + kc * 16 + h2 * 8 + e;
    const float* src = tsel == 0 ? qw1 : tsel == 1 ? kw1 : tsel == 2 ? vw1 : rw1;
    v = src[j];
  } else if (i < 98304) {
    int k = i - 32768;
    int tsel = k >> 14, d = k & 16383;
    int e = d & 7, lane = (d >> 3) & 63, kc = (d >> 9) & 7, h = (d >> 12) & 3;
    int col = lane & 31, h2 = lane >> 5;
    int j = (h * 32 + col) * 128 + kc * 16 + h2 * 8 + e;
    const float* src = tsel == 0 ? qw2 : tsel == 1 ? kw2 : tsel == 2 ? vw2 : rw2;
    v = src[j];
  } else {
    int d = i - 98304;
    int r = d & 3, lane = (d >> 2) & 63, g = (d >> 8) & 3, h = (d >> 10) & 3;
    int col = lane & 31, h2 = lane >> 5;
    v = lw[(8 * g + 4 * h2 + r) * 128 + h * 32 + col];
  }
  outw[i] = f2bf(v);
}

extern "C" void kernel_launch(void* const* d_in, const int* in_sizes, int n_in,
                              void* d_out, int out_size, void* d_ws, size_t ws_size,
                              hipStream_t stream) {
  short* wbf = (short*)d_ws;  // 204800 bytes used
  convert_w<<<400, 256, 0, stream>>>(
      (const float*)d_in[7], (const float*)d_in[9], (const float*)d_in[11],
      (const float*)d_in[13], (const float*)d_in[15], (const float*)d_in[17],
      (const float*)d_in[19], (const float*)d_in[21], (const float*)d_in[23], wbf);
  autoint_main<<<NSAMP / 2, 256, 0, stream>>>(
      (const int*)d_in[0], (const float*)d_in[1], (const int*)d_in[2],
      (const float*)d_in[3], (const float*)d_in[4], (const float*)d_in[5],
      (const float*)d_in[6],
      (const float*)d_in[8], (const float*)d_in[10], (const float*)d_in[12],
      (const float*)d_in[14], (const float*)d_in[16], (const float*)d_in[18],
      (const float*)d_in[20], (const float*)d_in[22], (const float*)d_in[24],
      wbf, (float*)d_out);
}

// Round 15
// 224.429 us; speedup vs baseline: 1.1835x; 1.0769x over previous
//
#include <hip/hip_runtime.h>
#include <hip/hip_bf16.h>

// AutoInt fused: embedding gather -> 2x MHSA (32 fields, 4 heads x 32) -> logit.
// Lineage: 2 samples/wave, rcp_fast + paired cvt, fragment-ordered W, batch
// gathers, rolling pre[4] W prefetch, swizzled disjoint y2, direct mh loads,
// swapped-QK^T in-register P (R26, 140.5us).
// R27: ZERO-LDS ATTENTION. V's tile round-trip is also pure rearrangement:
//     normal V-proj output -> PV B-frag via the SAME buildFrag transform
//     (store path packed pack2(acc[4g],acc[4g+1])/(acc[4g+2],acc[4g+3]) and
//     the read window reassembled own+partner quads == xchg). Q,K in-reg via
//     projSwp (R25-proven). Liveness-ordered phases: Q->afq, K->afk, S->pa
//     (afq/afk die), V->vb (acc dies), R->res last w/ WnlQ prefetch: peak
//     ~144 regs (R26 budget; R25's 176 spilled). Tiles gone -> y1 gets its
//     own region -> L1 in-layer barrier gone. Barriers 4 -> 3. LDS 53,248 ->
//     25,600B. Logit partials reuse dead y1. Bit-identical math.

#define NSAMP 8192
#define S_Y1 72    // layer1 input stride (shorts)

typedef __attribute__((ext_vector_type(8))) short bf8_t;   // 8 bf16 (4 VGPRs)
typedef __attribute__((ext_vector_type(16))) float f16v;   // 32x32 C/D

__device__ __forceinline__ short f2bf(float f) {
  unsigned u = __float_as_uint(f);
  u += 0x7fffu + ((u >> 16) & 1u);   // RNE
  return (short)(u >> 16);
}
// packed RNE f32x2 -> bf16x2; a -> low 16, b -> high 16 (HIP header semantics)
__device__ __forceinline__ unsigned pack2(float a, float b) {
  __hip_bfloat162 h = __float22bfloat162_rn(float2{a, b});
  union { __hip_bfloat162 h2; unsigned u; } cvt;
  cvt.h2 = h;
  return cvt.u;
}
__device__ __forceinline__ float bf2f(short s) {
  return __uint_as_float(((unsigned)(unsigned short)s) << 16);
}
__device__ __forceinline__ float rcp_fast(float x) {
  return __builtin_amdgcn_rcpf(x);   // v_rcp_f32, ~1ulp; sums>0 always
}
__device__ __forceinline__ f16v mfma32(bf8_t a, bf8_t b, f16v c) {
  return __builtin_amdgcn_mfma_f32_32x32x16_bf16(a, b, c, 0, 0, 0);
}

// Rebuild an A/B fragment from a C-layout quad pair (proven bit-exact in R25
// end-to-end and R26). Own lane holds quads g=2kc, 2kc+1; partner (lane^32)
// holds the complementary h2-half.
__device__ __forceinline__ bf8_t xchg(unsigned a01, unsigned a23,
                                      unsigned b01, unsigned b23, int h2) {
  unsigned pa01 = (unsigned)__shfl_xor((int)a01, 32);
  unsigned pa23 = (unsigned)__shfl_xor((int)a23, 32);
  unsigned pb01 = (unsigned)__shfl_xor((int)b01, 32);
  unsigned pb23 = (unsigned)__shfl_xor((int)b23, 32);
  union { bf8_t v; unsigned u[4]; } r;
  r.u[0] = h2 ? pb01 : a01;
  r.u[1] = h2 ? pb23 : a23;
  r.u[2] = h2 ? b01 : pa01;
  r.u[3] = h2 ? b23 : pa23;
  return r.v;
}

// C-layout 16 f32 (regs = k-dims (r&3)+8*(r>>2)+4*h2) -> two K=16 fragments.
__device__ __forceinline__ void buildFrag(const f16v& o, int h2, bf8_t (&dst)[2]) {
#pragma unroll
  for (int kc = 0; kc < 2; ++kc) {
    unsigned a01 = pack2(o[8 * kc + 0], o[8 * kc + 1]);
    unsigned a23 = pack2(o[8 * kc + 2], o[8 * kc + 3]);
    unsigned b01 = pack2(o[8 * kc + 4], o[8 * kc + 5]);
    unsigned b23 = pack2(o[8 * kc + 6], o[8 * kc + 7]);
    dst[kc] = xchg(a01, a23, b01, b23, h2);
  }
}

// NORMAL projection (C = y.W^T + b): lane col = out-dim, regs = fields.
template<int KS, bool HAS_NEXT>
__device__ __forceinline__ void projPF(const bf8_t (&af)[2][KS],
                                       const short* __restrict__ W,
                                       const float* __restrict__ bias,
                                       int fragBase,
                                       const short* __restrict__ Wnext,
                                       int fbNext, int n0, int col,
                                       bf8_t (&pre)[4], f16v (&o)[2]) {
  constexpr int PF = (KS < 4) ? KS : 4;
  bf8_t nxt[4];
  if constexpr (HAS_NEXT) {
#pragma unroll
    for (int i = 0; i < 4; ++i)
      nxt[i] = *(const bf8_t*)&Wnext[fbNext + i * 512];
  }
  float bb = bias[n0 + col];
#pragma unroll
  for (int i = 0; i < 16; ++i) { o[0][i] = bb; o[1][i] = bb; }
#pragma unroll
  for (int kc = 0; kc < KS; ++kc) {
    bf8_t w;
    if (kc < PF) w = pre[kc];
    else w = *(const bf8_t*)&W[fragBase + kc * 512];
    o[0] = mfma32(af[0][kc], w, o[0]);
    o[1] = mfma32(af[1][kc], w, o[1]);
  }
  if constexpr (HAS_NEXT) {
#pragma unroll
    for (int i = 0; i < 4; ++i) pre[i] = nxt[i];
  }
}

// SWAPPED projection (C^T = W.y^T): lane col = FIELD, regs = out-dims.
// Bias per-reg: o[4g+r] = bias[n0 + 8g + 4h2 + r] (same logical element as
// normal orientation -> bit-identical). Proven in R25's bit-exact run.
template<int KS, bool HAS_NEXT>
__device__ __forceinline__ void projSwp(const bf8_t (&af)[2][KS],
                                        const short* __restrict__ W,
                                        const float* __restrict__ bias,
                                        int fragBase,
                                        const short* __restrict__ Wnext,
                                        int fbNext, int n0, int h2,
                                        bf8_t (&pre)[4], f16v (&o)[2]) {
  constexpr int PF = (KS < 4) ? KS : 4;
  bf8_t nxt[4];
  if constexpr (HAS_NEXT) {
#pragma unroll
    for (int i = 0; i < 4; ++i)
      nxt[i] = *(const bf8_t*)&Wnext[fbNext + i * 512];
  }
#pragma unroll
  for (int g = 0; g < 4; ++g) {
    float4 b4 = *(const float4*)&bias[n0 + 8 * g + 4 * h2];
    o[0][4 * g + 0] = b4.x; o[0][4 * g + 1] = b4.y;
    o[0][4 * g + 2] = b4.z; o[0][4 * g + 3] = b4.w;
    o[1][4 * g + 0] = b4.x; o[1][4 * g + 1] = b4.y;
    o[1][4 * g + 2] = b4.z; o[1][4 * g + 3] = b4.w;
  }
#pragma unroll
  for (int kc = 0; kc < KS; ++kc) {
    bf8_t w;
    if (kc < PF) w = pre[kc];
    else w = *(const bf8_t*)&W[fragBase + kc * 512];
    o[0] = mfma32(w, af[0][kc], o[0]);   // operands swapped -> C^T
    o[1] = mfma32(w, af[1][kc], o[1]);
  }
  if constexpr (HAS_NEXT) {
#pragma unroll
    for (int i = 0; i < 4; ++i) pre[i] = nxt[i];
  }
}

// One attention layer, this wave's head, BOTH samples. ZERO LDS inside:
// Q,K via projSwp -> frags; P via swapped S + in-reg exp; V via projPF ->
// buildFrag (same transform as the old tile round-trip). Liveness-ordered:
// Q->afq, K->afk, S->pa, V->vb, R->res(last, carries WnlQ prefetch).
template<int D_IN, bool FUSE>
__device__ void attn_layer(const short* yIn0, const short* yIn1,
                           short* yOut0, short* yOut1,
                           const short* __restrict__ Wq, const short* __restrict__ Wk,
                           const short* __restrict__ Wv, const short* __restrict__ Wr,
                           const float* __restrict__ bq, const float* __restrict__ bk,
                           const float* __restrict__ bvp, const float* __restrict__ br,
                           const short* __restrict__ lwF,
                           const short* __restrict__ WnlQ, int fbNext,
                           int n0, int col, int h2, bf8_t (&pre)[4],
                           float (&pp)[2]) {
  constexpr int KS = D_IN / 16;
  const short* yIn[2] = {yIn0, yIn1};
  const int head = n0 >> 5;
  const int lane = h2 * 32 + col;
  const int fragBase = head * KS * 512 + lane * 8;

  // A-fragments for both samples
  bf8_t af[2][KS];
#pragma unroll
  for (int sp = 0; sp < 2; ++sp)
#pragma unroll
    for (int kc = 0; kc < KS; ++kc) {
      if constexpr (FUSE) {
        int gsw = (kc * 2 + h2) ^ (col & 15);
        af[sp][kc] = *(const bf8_t*)&yIn[sp][col * 128 + (gsw << 3)];
      } else {
        af[sp][kc] = *(const bf8_t*)&yIn[sp][col * S_Y1 + kc * 16 + h2 * 8];
      }
    }

  f16v acc[2];

  // ---- Q swapped (prefetches Wk) -> afq
  bf8_t afq[2][2];
  projSwp<KS, true>(af, Wq, bq, fragBase, Wk, fragBase, n0, h2, pre, acc);
  buildFrag(acc[0], h2, afq[0]);
  buildFrag(acc[1], h2, afq[1]);

  // ---- K swapped (prefetches Wv) -> afk
  bf8_t afk[2][2];
  projSwp<KS, true>(af, Wk, bk, fragBase, Wv, fragBase, n0, h2, pre, acc);
  buildFrag(acc[0], h2, afk[0]);
  buildFrag(acc[1], h2, afk[1]);

  // ---- S^T = mfma(afk, afq); exp in-register -> pa (afq/afk die here)
  bf8_t pa[2][2];
#pragma unroll
  for (int sp = 0; sp < 2; ++sp) {
    f16v z;
#pragma unroll
    for (int i = 0; i < 16; ++i) z[i] = 0.f;
#pragma unroll
    for (int kc = 0; kc < 2; ++kc)
      z = mfma32(afk[sp][kc], afq[sp][kc], z);
    f16v e;
#pragma unroll
    for (int i = 0; i < 16; ++i) e[i] = __expf(z[i]);
    buildFrag(e, h2, pa[sp]);
  }

  // ---- V normal (prefetches Wr) -> vb (acc dies after buildFrag)
  bf8_t vb[2][2];
  projPF<KS, true>(af, Wv, bvp, fragBase, Wr, fragBase, n0, col, pre, acc);
  buildFrag(acc[0], h2, vb[0]);
  buildFrag(acc[1], h2, vb[1]);

  // ---- Res normal (layer1: prefetches next layer's Wq; layer2: none)
  f16v res[2];
  projPF<KS, !FUSE>(af, Wr, br, fragBase, WnlQ, fbNext, n0, col, pre, res);

  // ---- FUSE: hoist logit-weight loads above the PV chain
  short4 l4b[4];
  if constexpr (FUSE) {
#pragma unroll
    for (int g = 0; g < 4; ++g)
      l4b[g] = *(const short4*)&lwF[(head * 4 + g) * 256 + lane * 4];
  }

  // ---- PV + row-sums (all-ones B-frag), fully in-register
  const short onebf = (short)0x3F80;
  bf8_t ones = {onebf, onebf, onebf, onebf, onebf, onebf, onebf, onebf};
  f16v pv[2], sums[2];
#pragma unroll
  for (int sp = 0; sp < 2; ++sp) {
#pragma unroll
    for (int i = 0; i < 16; ++i) { pv[sp][i] = 0.f; sums[sp][i] = 0.f; }
#pragma unroll
    for (int kc = 0; kc < 2; ++kc) {
      pv[sp] = mfma32(pa[sp][kc], vb[sp][kc], pv[sp]);
      sums[sp] = mfma32(pa[sp][kc], ones, sums[sp]);
    }
  }

  if constexpr (FUSE) {
#pragma unroll
    for (int g = 0; g < 4; ++g) {
      short4 l4 = l4b[g];
#pragma unroll
      for (int r = 0; r < 4; ++r) {
        int reg = g * 4 + r;
        float lw = bf2f((r == 0) ? l4.x : (r == 1) ? l4.y : (r == 2) ? l4.z : l4.w);
        pp[0] += fmaxf(fmaf(pv[0][reg], rcp_fast(sums[0][reg]), res[0][reg]), 0.f) * lw;
        pp[1] += fmaxf(fmaf(pv[1][reg], rcp_fast(sums[1][reg]), res[1][reg]), 0.f) * lw;
      }
    }
  } else {
    // Swizzled y2 write; y2s disjoint from everything -> NO barrier needed.
    short* yOut[2] = {yOut0, yOut1};
    const int cg = head * 4 + (col >> 3);   // column granule
    const int cw = col & 7;                  // within-granule
#pragma unroll
    for (int sp = 0; sp < 2; ++sp)
#pragma unroll
      for (int g = 0; g < 4; ++g) {
        float v[4];
#pragma unroll
        for (int r = 0; r < 4; ++r)
          v[r] = fmaxf(fmaf(pv[sp][4 * g + r], rcp_fast(sums[sp][4 * g + r]),
                            res[sp][4 * g + r]), 0.f);
        unsigned p01 = pack2(v[0], v[1]);
        unsigned p23 = pack2(v[2], v[3]);
        int rb = 8 * g + 4 * h2;
        short s4[4] = {(short)(p01 & 0xffffu), (short)(p01 >> 16),
                       (short)(p23 & 0xffffu), (short)(p23 >> 16)};
#pragma unroll
        for (int r = 0; r < 4; ++r) {
          int row = rb + r;
          yOut[sp][row * 128 + ((cg ^ (row & 15)) << 3) + cw] = s4[r];
        }
      }
  }
}

__global__ __launch_bounds__(256, 3) void autoint_main(
    const int* __restrict__ onehot_i, const float* __restrict__ onehot_x,
    const int* __restrict__ mh_i, const float* __restrict__ mh_x,
    const float* __restrict__ ctns, const float* __restrict__ xx,
    const float* __restrict__ xy,
    const float* __restrict__ bq1, const float* __restrict__ bk1,
    const float* __restrict__ bv1, const float* __restrict__ br1,
    const float* __restrict__ bq2, const float* __restrict__ bk2,
    const float* __restrict__ bv2, const float* __restrict__ br2,
    const float* __restrict__ logitb, const short* __restrict__ wbf,
    float* __restrict__ out) {
  // y1s: layer1 input [32 rows][stride 72] per sample, own region (no
  // overlay -> no in-layer barrier). Logit partials reuse its dead space.
  // y2s: disjoint XOR-swizzled y2 [32][128] per sample.
  // Total LDS = 9,216 + 16,384 = 25,600 B -> ~26,624 granule -> 3 blocks/CU
  // (register-capped; LDS would allow 6).
  __shared__ __align__(16) short y1s[2][2304];
  __shared__ __align__(16) short y2s[2][4096];

  const int t = threadIdx.x;
  const int head = t >> 6;
  const int lane = t & 63;
  const int col = lane & 31;
  const int h2 = lane >> 5;
  const int n0 = head * 32;
  const int s0 = blockIdx.x * 2;

  // ---- rolling W prefetch: Wq1 frags 0..3 issued NOW, hidden under embedding
  const int fb1 = head * 4 * 512 + lane * 8;
  const int fb2 = head * 8 * 512 + lane * 8;
  bf8_t pre[4];
#pragma unroll
  for (int i = 0; i < 4; ++i) pre[i] = *(const bf8_t*)&wbf[fb1 + i * 512];

  const int e4 = t & 15, f0 = t >> 4;

  // ---- E0: onehot scalars + ctns/xy
  int oh_r[2][2]; float oh_w[2][2];        // [chunk][se]
#pragma unroll
  for (int se = 0; se < 2; ++se) {
    oh_r[0][se] = onehot_i[(s0 + se) * 20 + f0];
    oh_w[0][se] = onehot_x[(s0 + se) * 20 + f0];
  }
  if (t < 64) {
#pragma unroll
    for (int se = 0; se < 2; ++se) {
      oh_r[1][se] = onehot_i[(s0 + se) * 20 + 16 + f0];
      oh_w[1][se] = onehot_x[(s0 + se) * 20 + 16 + f0];
    }
  }
  if (t < 160) {                           // ctns: rows 22..31
    int ci = t >> 4;
    float4 xv = *(const float4*)&xy[ci * 64 + e4 * 4];
    float cv0 = ctns[(s0 + 0) * 10 + ci];
    float cv1 = ctns[(s0 + 1) * 10 + ci];
    uint2 w0; w0.x = pack2(cv0 * xv.x, cv0 * xv.y); w0.y = pack2(cv0 * xv.z, cv0 * xv.w);
    *(uint2*)&y1s[0][(22 + ci) * S_Y1 + e4 * 4] = w0;
    uint2 w1; w1.x = pack2(cv1 * xv.x, cv1 * xv.y); w1.y = pack2(cv1 * xv.z, cv1 * xv.w);
    *(uint2*)&y1s[1][(22 + ci) * S_Y1 + e4 * 4] = w1;
  }

  // ---- E2a: onehot gathers issue (fly alongside mh idx reads + gathers)
  float4 g0[2], g1[2];
#pragma unroll
  for (int se = 0; se < 2; ++se)
    g0[se] = *(const float4*)&xx[oh_r[0][se] * 64 + e4 * 4];
  if (t < 64) {
#pragma unroll
    for (int se = 0; se < 2; ++se)
      g1[se] = *(const float4*)&xx[oh_r[1][se] * 64 + e4 * 4];
  }

  // ---- E1: multihot, DIRECT global idx/weight loads (wave-merged, L2-hot),
  //      7-deep batch-issued gathers (k padded to 56), 8-lane shfl reduce.
  {
    const int slot = t >> 3, ks = t & 7;
    const int j = slot >> 4, e4m = slot & 15;
#pragma unroll
    for (int se = 0; se < 2; ++se) {
      const int sg = s0 + se;
      const int* ip = &mh_i[(j * NSAMP + sg) * 50];
      const float* xp = &mh_x[(j * NSAMP + sg) * 50];
      int rw[7]; float wt[7];
#pragma unroll
      for (int i = 0; i < 7; ++i) {
        int k = ks + 8 * i;
        int ok = (k < 50);
        rw[i] = ok ? ip[k] : 0;
        wt[i] = ok ? xp[k] : 0.f;
      }
      float4 xv[7];
#pragma unroll
      for (int i = 0; i < 7; ++i)
        xv[i] = *(const float4*)&xx[rw[i] * 64 + e4m * 4];
      float a0 = 0.f, a1 = 0.f, a2 = 0.f, a3 = 0.f;
#pragma unroll
      for (int i = 0; i < 7; ++i) {
        a0 += xv[i].x * wt[i]; a1 += xv[i].y * wt[i];
        a2 += xv[i].z * wt[i]; a3 += xv[i].w * wt[i];
      }
#pragma unroll
      for (int d = 1; d < 8; d <<= 1) {
        a0 += __shfl_xor(a0, d); a1 += __shfl_xor(a1, d);
        a2 += __shfl_xor(a2, d); a3 += __shfl_xor(a3, d);
      }
      if (ks == 0) {
        uint2 w; w.x = pack2(a0, a1); w.y = pack2(a2, a3);
        *(uint2*)&y1s[se][(20 + j) * S_Y1 + e4m * 4] = w;
      }
    }
  }

  // ---- E2b: onehot scale + store (gathers long since landed)
#pragma unroll
  for (int se = 0; se < 2; ++se) {
    float xw = oh_w[0][se];
    uint2 w; w.x = pack2(g0[se].x * xw, g0[se].y * xw);
    w.y = pack2(g0[se].z * xw, g0[se].w * xw);
    *(uint2*)&y1s[se][f0 * S_Y1 + e4 * 4] = w;
  }
  if (t < 64) {
#pragma unroll
    for (int se = 0; se < 2; ++se) {
      float xw = oh_w[1][se];
      uint2 w; w.x = pack2(g1[se].x * xw, g1[se].y * xw);
      w.y = pack2(g1[se].z * xw, g1[se].w * xw);
      *(uint2*)&y1s[se][(16 + f0) * S_Y1 + e4 * 4] = w;
    }
  }
  __syncthreads();   // y1 complete

  float pp[2] = {0.f, 0.f};
  attn_layer<64, false>(&y1s[0][0], &y1s[1][0], &y2s[0][0], &y2s[1][0],
      wbf + 0, wbf + 8192, wbf + 16384, wbf + 24576,
      bq1, bk1, bv1, br1, nullptr,
      wbf + 32768, fb2, n0, col, h2, pre, pp);
  __syncthreads();   // y2s fully written before layer2 af reads
  attn_layer<128, true>(&y2s[0][0], &y2s[1][0], nullptr, nullptr,
      wbf + 32768, wbf + 49152, wbf + 65536, wbf + 81920,
      bq2, bk2, bv2, br2, wbf + 98304,
      wbf, 0, n0, col, h2, pre, pp);

  // ---- logit partials: wave-reduce each sample; partials in dead y1 space
  //      (all y1 reads completed before the transition barrier).
  float* red0 = (float*)&y1s[0][0];
  float* red1 = (float*)&y1s[1][0];
#pragma unroll
  for (int off = 32; off > 0; off >>= 1) {
    pp[0] += __shfl_xor(pp[0], off);
    pp[1] += __shfl_xor(pp[1], off);
  }
  if (lane == 0) { red0[head] = pp[0]; red1[head] = pp[1]; }
  __syncthreads();
  if (t < 2) {
    const float* rp = t == 0 ? red0 : red1;
    float zz = rp[0] + rp[1] + rp[2] + rp[3] + logitb[0];
    out[s0 + t] = 1.f / (1.f + __expf(-zz));
  }
}

// fp32 -> bf16 weight conversion into ws, FRAGMENT-ORDERED:
// [0)Wq1F [8192)Wk1F [16384)Wv1F [24576)Wr1F   each ((h*4+kc)*64+lane)*8+e
// [32768)Wq2F [49152)Wk2F [65536)Wv2F [81920)Wr2F  ((h*8+kc)*64+lane)*8+e
// [98304)lwF ((h*4+g)*64+lane)*4+r = lw[(8g+4h2+r)*128 + h*32+col]
__global__ void convert_w(const float* __restrict__ qw1, const float* __restrict__ kw1,
                          const float* __restrict__ vw1, const float* __restrict__ rw1,
                          const float* __restrict__ qw2, const float* __restrict__ kw2,
                          const float* __restrict__ vw2, const float* __restrict__ rw2,
                          const float* __restrict__ lw, short* __restrict__ outw) {
  int i = blockIdx.x * 256 + threadIdx.x;
  if (i >= 102400) return;
  float v;
  if (i < 32768) {
    int tsel = i >> 13, d = i & 8191;
    int e = d & 7, lane = (d >> 3) & 63, kc = (d >> 9) & 3, h = (d >> 11) & 3;
    int col = lane & 31, h2 = lane >> 5;
    int j = (h * 32 + col) * 64 + kc * 16 + h2 * 8 + e;
    const float* src = tsel == 0 ? qw1 : tsel == 1 ? kw1 : tsel == 2 ? vw1 : rw1;
    v = src[j];
  } else if (i < 98304) {
    int k = i - 32768;
    int tsel = k >> 14, d = k & 16383;
    int e = d & 7, lane = (d >> 3) & 63, kc = (d >> 9) & 7, h = (d >> 12) & 3;
    int col = lane & 31, h2 = lane >> 5;
    int j = (h * 32 + col) * 128 + kc * 16 + h2 * 8 + e;
    const float* src = tsel == 0 ? qw2 : tsel == 1 ? kw2 : tsel == 2 ? vw2 : rw2;
    v = src[j];
  } else {
    int d = i - 98304;
    int r = d & 3, lane = (d >> 2) & 63, g = (d >> 8) & 3, h = (d >> 10) & 3;
    int col = lane & 31, h2 = lane >> 5;
    v = lw[(8 * g + 4 * h2 + r) * 128 + h * 32 + col];
  }
  outw[i] = f2bf(v);
}

extern "C" void kernel_launch(void* const* d_in, const int* in_sizes, int n_in,
                              void* d_out, int out_size, void* d_ws, size_t ws_size,
                              hipStream_t stream) {
  short* wbf = (short*)d_ws;  // 204800 bytes used
  convert_w<<<400, 256, 0, stream>>>(
      (const float*)d_in[7], (const float*)d_in[9], (const float*)d_in[11],
      (const float*)d_in[13], (const float*)d_in[15], (const float*)d_in[17],
      (const float*)d_in[19], (const float*)d_in[21], (const float*)d_in[23], wbf);
  autoint_main<<<NSAMP / 2, 256, 0, stream>>>(
      (const int*)d_in[0], (const float*)d_in[1], (const int*)d_in[2],
      (const float*)d_in[3], (const float*)d_in[4], (const float*)d_in[5],
      (const float*)d_in[6],
      (const float*)d_in[8], (const float*)d_in[10], (const float*)d_in[12],
      (const float*)d_in[14], (const float*)d_in[16], (const float*)d_in[18],
      (const float*)d_in[20], (const float*)d_in[22], (const float*)d_in[24],
      wbf, (float*)d_out);
}